// Round 14
// baseline (3705.517 us; speedup 1.0000x reference)
//
#include <hip/hip_runtime.h>
#include <math.h>

#define T_TOK 16384
#define DDIM 2048
#define NEXP 256
#define TOPK 8
#define NLIM 4
#define CAPN 6144

constexpr float EPSC = 1e-5f;         // certified score-space error bound
constexpr float SCL = 1.f / 4096.f;   // undo x*16, w*256 scaling

typedef _Float16 half4v __attribute__((ext_vector_type(4)));
typedef _Float16 half8v __attribute__((ext_vector_type(8)));
typedef float f32x4 __attribute__((ext_vector_type(4)));

// ---------------- K0: convert w to fp16 hi/lo + init counts/worklist -------
__global__ __launch_bounds__(256) void prep(
    const float* __restrict__ w, _Float16* __restrict__ wh,
    _Float16* __restrict__ wlo, float* __restrict__ counts,
    int* __restrict__ wl_count) {
  int gid = blockIdx.x * 256 + threadIdx.x;
  float W = w[gid] * 256.f;
  _Float16 h = (_Float16)W;
  wh[gid] = h;
  wlo[gid] = (_Float16)(W - (float)h);
  if (blockIdx.x == 0) {
    counts[threadIdx.x] = 0.f;
    if (threadIdx.x == 0) *wl_count = 0;
  }
}

// --- K1: MFMA gate GEMM (r9 geometry) + 2-deep register prefetch -----------
constexpr int BM = 64, BN = 128, BK = 64, NT = DDIM / BK;  // NT=32
__global__ __launch_bounds__(256) void gate_gemm_mfma(
    const float* __restrict__ x, const _Float16* __restrict__ wh,
    const _Float16* __restrict__ wlo, float* __restrict__ scores) {
  __shared__ _Float16 Ah[64][72], Al[64][72];
  __shared__ _Float16 Bh[128][72], Bl[128][72];
  const int tid = threadIdx.x;
  const int bid = blockIdx.x;
  const int mb = bid >> 1, nb = bid & 1;
  const int row0 = mb * BM, col0 = nb * BN;
  const int wave = tid >> 6, lane = tid & 63;
  const int m0 = (wave >> 1) * 32, n0 = (wave & 1) * 64;

  f32x4 acc[2][4];
#pragma unroll
  for (int i = 0; i < 2; i++)
#pragma unroll
    for (int j = 0; j < 4; j++) acc[i][j] = (f32x4){0.f, 0.f, 0.f, 0.f};

  // 2-deep register staging: slot s holds tile t with t%2==s
  float4 ar[2][4];
  half8v brh[2][4], brl[2][4];

  auto LOADT = [&](int t, int s) {
    const int k0 = t * BK;
#pragma unroll
    for (int i = 0; i < 4; i++) {
      int f = i * 256 + tid;
      int r = f >> 4, c4 = (f & 15) << 2;
      ar[s][i] = *reinterpret_cast<const float4*>(
          x + (size_t)(row0 + r) * DDIM + k0 + c4);
    }
#pragma unroll
    for (int i = 0; i < 4; i++) {
      int f = i * 256 + tid;
      int r = f >> 3, k8 = (f & 7) << 3;
      size_t g = (size_t)(col0 + r) * DDIM + k0 + k8;
      brh[s][i] = *reinterpret_cast<const half8v*>(wh + g);
      brl[s][i] = *reinterpret_cast<const half8v*>(wlo + g);
    }
  };
  auto WRITET = [&](int s) {
#pragma unroll
    for (int i = 0; i < 4; i++) {
      int f = i * 256 + tid;
      int r = f >> 4, c4 = (f & 15) << 2;
      float4 v = ar[s][i];
      float X0 = v.x * 16.f, X1 = v.y * 16.f, X2 = v.z * 16.f, X3 = v.w * 16.f;
      _Float16 h0 = (_Float16)X0, h1 = (_Float16)X1;
      _Float16 h2 = (_Float16)X2, h3 = (_Float16)X3;
      half4v hv = {h0, h1, h2, h3};
      half4v lv = {(_Float16)(X0 - (float)h0), (_Float16)(X1 - (float)h1),
                   (_Float16)(X2 - (float)h2), (_Float16)(X3 - (float)h3)};
      *reinterpret_cast<half4v*>(&Ah[r][c4]) = hv;
      *reinterpret_cast<half4v*>(&Al[r][c4]) = lv;
    }
#pragma unroll
    for (int i = 0; i < 4; i++) {
      int f = i * 256 + tid;
      int r = f >> 3, k8 = (f & 7) << 3;
      *reinterpret_cast<half8v*>(&Bh[r][k8]) = brh[s][i];
      *reinterpret_cast<half8v*>(&Bl[r][k8]) = brl[s][i];
    }
  };

  LOADT(0, 0);
  LOADT(1, 1);
  for (int t = 0; t < NT; t++) {
    const int s = t & 1;
    WRITET(s);  // tile t regs -> LDS (loads issued 2 iters ago: no vm wait)
    __syncthreads();
    if (t + 2 < NT) LOADT(t + 2, s);  // refill freed slot; 2 tiles in flight
#pragma unroll
    for (int ks = 0; ks < 2; ks++) {
      const int koff = ks * 32 + (lane >> 4) * 8;
      half8v ah[2], al[2], bh[4], bl[4];
#pragma unroll
      for (int mf = 0; mf < 2; mf++) {
        int r = m0 + mf * 16 + (lane & 15);
        ah[mf] = *reinterpret_cast<half8v*>(&Ah[r][koff]);
        al[mf] = *reinterpret_cast<half8v*>(&Al[r][koff]);
      }
#pragma unroll
      for (int nf = 0; nf < 4; nf++) {
        int c = n0 + nf * 16 + (lane & 15);
        bh[nf] = *reinterpret_cast<half8v*>(&Bh[c][koff]);
        bl[nf] = *reinterpret_cast<half8v*>(&Bl[c][koff]);
      }
#pragma unroll
      for (int mf = 0; mf < 2; mf++)
#pragma unroll
        for (int nf = 0; nf < 4; nf++) {
          acc[mf][nf] = __builtin_amdgcn_mfma_f32_16x16x32_f16(
              ah[mf], bh[nf], acc[mf][nf], 0, 0, 0);
          acc[mf][nf] = __builtin_amdgcn_mfma_f32_16x16x32_f16(
              ah[mf], bl[nf], acc[mf][nf], 0, 0, 0);
          acc[mf][nf] = __builtin_amdgcn_mfma_f32_16x16x32_f16(
              al[mf], bh[nf], acc[mf][nf], 0, 0, 0);
        }
    }
    __syncthreads();
  }
  // epilogue: sigmoid, plain stores
#pragma unroll
  for (int mf = 0; mf < 2; mf++)
#pragma unroll
    for (int nf = 0; nf < 4; nf++)
#pragma unroll
      for (int r = 0; r < 4; r++) {
        int row = row0 + m0 + mf * 16 + (lane >> 4) * 4 + r;
        int col = col0 + n0 + nf * 16 + (lane & 15);
        float sv = 1.f / (1.f + expf(-acc[mf][nf][r] * SCL));
        scores[(size_t)row * NEXP + col] = sv;
      }
}

// -------- K2: serial-lane router: one lane per token, u64-key top-9 --------
__global__ __launch_bounds__(64) void router_serial(
    const float* __restrict__ scores, const float* __restrict__ bias,
    float* __restrict__ out_scores, float* __restrict__ out_sel,
    float* __restrict__ out_counts, int* __restrict__ wl_count,
    int* __restrict__ wlist) {
  __shared__ float S[64][257];  // biased scores; stride 257 -> 2-way banks
  __shared__ float BS[256];
  __shared__ int hist[256];
  const int lane = threadIdx.x;
  const int t0 = blockIdx.x * 64;

#pragma unroll
  for (int i = 0; i < 4; i++) {
    hist[i * 64 + lane] = 0;
    BS[i * 64 + lane] = bias[i * 64 + lane];
  }
  float4 bv = *reinterpret_cast<const float4*>(bias + lane * 4);
  for (int r = 0; r < 64; r++) {
    float4 v = *reinterpret_cast<const float4*>(
        scores + (size_t)(t0 + r) * NEXP + lane * 4);
    S[r][lane * 4 + 0] = v.x + bv.x;
    S[r][lane * 4 + 1] = v.y + bv.y;
    S[r][lane * 4 + 2] = v.z + bv.z;
    S[r][lane * 4 + 3] = v.w + bv.w;
  }
  __syncthreads();

  const float* Srow = S[lane];
  const int t = t0 + lane;

  // phase A: per-group top-2 sums
  float gsArr[8];
#pragma unroll
  for (int g = 0; g < 8; g++) {
    float m1 = -INFINITY, m2 = -INFINITY;
#pragma unroll 4
    for (int k = 0; k < 32; k++) {
      float c = Srow[g * 32 + k];
      float mx = fmaxf(m1, c);
      m2 = fmaxf(m2, fminf(m1, c));
      m1 = mx;
    }
    gsArr[g] = m1 + m2;
  }

  // group ranks -> kept nibble-pack, 4th/5th margin
  int kgpack = 0;
  float v4 = 0.f, v5 = 0.f;
#pragma unroll
  for (int g = 7; g >= 0; g--) {
    int rk = 0;
#pragma unroll
    for (int h = 0; h < 8; h++)
      rk += (gsArr[h] > gsArr[g]) || (gsArr[h] == gsArr[g] && h < g);
    if (rk < NLIM) kgpack = (kgpack << 4) | g;
    if (rk == 3) v4 = gsArr[g];
    if (rk == 4) v5 = gsArr[g];
  }
  bool flag = (v4 - v5) < 8.f * EPSC;

  // phase B: branchless 9-slot insertion over 128 eligible, u64 keys
  unsigned long long L[9];
#pragma unroll
  for (int i = 0; i < 9; i++) L[i] = 0ULL;
#pragma unroll
  for (int gi = 0; gi < 4; gi++) {
    const int cb = ((kgpack >> (gi * 4)) & 15) * 32;
#pragma unroll 2
    for (int k = 0; k < 32; k++) {
      float c = Srow[cb + k];
      unsigned int bits = __float_as_uint(c + 1.0f);
      unsigned long long key =
          ((unsigned long long)bits << 8) | (unsigned)(255 - (cb + k));
#pragma unroll
      for (int sl = 0; sl < 9; sl++) {
        bool gt = key > L[sl];
        unsigned long long nl = gt ? key : L[sl];
        key = gt ? L[sl] : key;
        L[sl] = nl;
      }
    }
  }

  int selE[9];
  float cval[9];
#pragma unroll
  for (int i = 0; i < 9; i++) {
    selE[i] = 255 - (int)(L[i] & 0xFFULL);
    cval[i] = __uint_as_float((unsigned)(L[i] >> 8)) - 1.0f;
  }
#pragma unroll
  for (int i = 0; i < 8; i++)
    flag = flag || ((cval[i] - cval[i + 1]) < 2.f * EPSC);

  if (!flag) {
    float s[8];
    float denom = 1e-20f;
#pragma unroll
    for (int i = 0; i < 8; i++) {
      s[i] = Srow[selE[i]] - BS[selE[i]];
      denom += s[i];
    }
    float scale = 2.5f / denom;
    float4 o0 = {s[0] * scale, s[1] * scale, s[2] * scale, s[3] * scale};
    float4 o1 = {s[4] * scale, s[5] * scale, s[6] * scale, s[7] * scale};
    *reinterpret_cast<float4*>(out_scores + (size_t)t * TOPK) = o0;
    *reinterpret_cast<float4*>(out_scores + (size_t)t * TOPK + 4) = o1;
    float4 e0 = {(float)selE[0], (float)selE[1], (float)selE[2], (float)selE[3]};
    float4 e1 = {(float)selE[4], (float)selE[5], (float)selE[6], (float)selE[7]};
    *reinterpret_cast<float4*>(out_sel + (size_t)t * TOPK) = e0;
    *reinterpret_cast<float4*>(out_sel + (size_t)t * TOPK + 4) = e1;
#pragma unroll
    for (int i = 0; i < 8; i++) atomicAdd(&hist[selE[i]], 1);
  } else {
    int i = atomicAdd(wl_count, 1);
    wlist[i] = t;
  }
  __syncthreads();
#pragma unroll
  for (int i = 0; i < 4; i++) {
    int h = hist[i * 64 + lane];
    if (h) atomicAdd(&out_counts[i * 64 + lane], (float)h);
  }
}

// ---- K3a: f64 logits for flagged tokens; block = (token-quad, 16 experts) -
__global__ __launch_bounds__(256) void fixup_logits(
    const float* __restrict__ x, const float* __restrict__ w,
    const int* __restrict__ wl_count, const int* __restrict__ wlist,
    double* __restrict__ scG) {
  __shared__ float xs[4][DDIM];  // 32 KB
  __shared__ int toks[4];
  const int n = min(*wl_count, CAPN);
  const int nq = (n + 3) >> 2;
  const int nwork = nq * 16;
  const int tid = threadIdx.x;
  const int wv = tid >> 6, lane = tid & 63;

  for (int wk = blockIdx.x; wk < nwork; wk += gridDim.x) {
    const int q = wk >> 4, ec = wk & 15;
    __syncthreads();
    if (tid < 4) {
      int idx = q * 4 + tid;
      toks[tid] = wlist[idx < n ? idx : (n - 1)];
    }
    __syncthreads();
    for (int i = tid; i < 4 * 512; i += 256) {
      int tk = i >> 9, off = i & 511;
      reinterpret_cast<float4*>(xs[tk])[off] =
          reinterpret_cast<const float4*>(x + (size_t)toks[tk] * DDIM)[off];
    }
    __syncthreads();

#pragma unroll 1
    for (int ei = 0; ei < 4; ei++) {
      const int e = ec * 16 + wv * 4 + ei;
      const float* wr = w + (size_t)e * DDIM + lane * 4;
      float4 wreg[8];
#pragma unroll
      for (int j = 0; j < 8; j++)
        wreg[j] = *reinterpret_cast<const float4*>(wr + j * 256);
      double p0 = 0, p1 = 0, p2 = 0, p3 = 0;
#pragma unroll
      for (int j = 0; j < 8; j++) {
        const int k = j * 256 + lane * 4;
        float4 wv4 = wreg[j];
        float4 x0 = *reinterpret_cast<const float4*>(&xs[0][k]);
        float4 x1 = *reinterpret_cast<const float4*>(&xs[1][k]);
        float4 x2 = *reinterpret_cast<const float4*>(&xs[2][k]);
        float4 x3 = *reinterpret_cast<const float4*>(&xs[3][k]);
        p0 = fma((double)x0.x, (double)wv4.x, p0);
        p0 = fma((double)x0.y, (double)wv4.y, p0);
        p0 = fma((double)x0.z, (double)wv4.z, p0);
        p0 = fma((double)x0.w, (double)wv4.w, p0);
        p1 = fma((double)x1.x, (double)wv4.x, p1);
        p1 = fma((double)x1.y, (double)wv4.y, p1);
        p1 = fma((double)x1.z, (double)wv4.z, p1);
        p1 = fma((double)x1.w, (double)wv4.w, p1);
        p2 = fma((double)x2.x, (double)wv4.x, p2);
        p2 = fma((double)x2.y, (double)wv4.y, p2);
        p2 = fma((double)x2.z, (double)wv4.z, p2);
        p2 = fma((double)x2.w, (double)wv4.w, p2);
        p3 = fma((double)x3.x, (double)wv4.x, p3);
        p3 = fma((double)x3.y, (double)wv4.y, p3);
        p3 = fma((double)x3.z, (double)wv4.z, p3);
        p3 = fma((double)x3.w, (double)wv4.w, p3);
      }
#pragma unroll
      for (int d = 1; d <= 32; d <<= 1) {
        p0 += __shfl_xor(p0, d);
        p1 += __shfl_xor(p1, d);
        p2 += __shfl_xor(p2, d);
        p3 += __shfl_xor(p3, d);
      }
      if (lane == 0) {
        const int it0 = q * 4;
        if (it0 + 0 < n) scG[(size_t)(it0 + 0) * NEXP + e] = 1.0 / (1.0 + exp(-p0));
        if (it0 + 1 < n) scG[(size_t)(it0 + 1) * NEXP + e] = 1.0 / (1.0 + exp(-p1));
        if (it0 + 2 < n) scG[(size_t)(it0 + 2) * NEXP + e] = 1.0 / (1.0 + exp(-p2));
        if (it0 + 3 < n) scG[(size_t)(it0 + 3) * NEXP + e] = 1.0 / (1.0 + exp(-p3));
      }
    }
  }
}

// ---- K3b: exact f64 selection per flagged token (reads scG) ---------------
__global__ __launch_bounds__(256) void fixup_select(
    const double* __restrict__ scG, const float* __restrict__ x,
    const float* __restrict__ w, const float* __restrict__ bias,
    float* __restrict__ out_scores, float* __restrict__ out_sel,
    float* __restrict__ out_counts, const int* __restrict__ wl_count,
    const int* __restrict__ wlist) {
  __shared__ double sc[NEXP];
  const int n = *wl_count;
  const int tid = threadIdx.x;
  const int wv = tid >> 6, lane = tid & 63;

  for (int it = blockIdx.x; it < n; it += gridDim.x) {
    const int t = wlist[it];
    __syncthreads();
    if (it < CAPN) {
      sc[tid] = scG[(size_t)it * NEXP + tid];
    } else {
      // fallback (never taken at observed n): compute inline
      const float* xrow = x + (size_t)t * DDIM + lane * 8;
      float4 xr[4][2];
#pragma unroll
      for (int p = 0; p < 4; p++) {
        xr[p][0] = *reinterpret_cast<const float4*>(xrow + p * 512);
        xr[p][1] = *reinterpret_cast<const float4*>(xrow + p * 512 + 4);
      }
      double myLogit = 0.0;
      for (int e = 0; e < 64; e++) {
        const float* wr = w + (size_t)(wv * 64 + e) * DDIM + lane * 8;
        double a0 = 0, a1 = 0;
#pragma unroll
        for (int p = 0; p < 4; p++) {
          float4 w0 = *reinterpret_cast<const float4*>(wr + p * 512);
          float4 w1 = *reinterpret_cast<const float4*>(wr + p * 512 + 4);
          a0 = fma((double)xr[p][0].x, (double)w0.x, a0);
          a1 = fma((double)xr[p][0].y, (double)w0.y, a1);
          a0 = fma((double)xr[p][0].z, (double)w0.z, a0);
          a1 = fma((double)xr[p][0].w, (double)w0.w, a1);
          a0 = fma((double)xr[p][1].x, (double)w1.x, a0);
          a1 = fma((double)xr[p][1].y, (double)w1.y, a1);
          a0 = fma((double)xr[p][1].z, (double)w1.z, a0);
          a1 = fma((double)xr[p][1].w, (double)w1.w, a1);
        }
        double tot = a0 + a1;
#pragma unroll
        for (int d = 1; d <= 32; d <<= 1) tot += __shfl_xor(tot, d);
        if (lane == e) myLogit = tot;
      }
      sc[wv * 64 + lane] = 1.0 / (1.0 + exp(-myLogit));
    }
    __syncthreads();

    if (tid < 64) {
      double s[4], c[4];
      s[0] = sc[lane * 4 + 0]; s[1] = sc[lane * 4 + 1];
      s[2] = sc[lane * 4 + 2]; s[3] = sc[lane * 4 + 3];
      float4 bvv = *reinterpret_cast<const float4*>(bias + lane * 4);
      c[0] = s[0] + (double)bvv.x; c[1] = s[1] + (double)bvv.y;
      c[2] = s[2] + (double)bvv.z; c[3] = s[3] + (double)bvv.w;

      double h1 = fmax(c[0], c[1]), l1 = fmin(c[0], c[1]);
      double h2 = fmax(c[2], c[3]), l2 = fmin(c[2], c[3]);
      double m1 = fmax(h1, h2);
      double m2 = fmax(fmin(h1, h2), fmax(l1, l2));
#pragma unroll
      for (int d = 1; d <= 4; d <<= 1) {
        double om1 = __shfl_xor(m1, d);
        double om2 = __shfl_xor(m2, d);
        double n1 = fmax(m1, om1);
        double n2 = fmax(fmin(m1, om1), fmax(m2, om2));
        m1 = n1; m2 = n2;
      }
      double gscore = m1 + m2;
      double gsv[8];
#pragma unroll
      for (int g = 0; g < 8; g++) gsv[g] = __shfl(gscore, g * 8);
      const int gme = lane >> 3;
      int rank = 0;
#pragma unroll
      for (int h = 0; h < 8; h++)
        rank += (gsv[h] > gsv[gme]) || (gsv[h] == gsv[gme] && h < gme);
      const bool keep = rank < NLIM;

      const double NEG = -HUGE_VAL;
      double v[4];
#pragma unroll
      for (int j = 0; j < 4; j++) v[j] = keep ? c[j] : NEG;

      double selS[TOPK];
      int selE[TOPK];
#pragma unroll
      for (int kk = 0; kk < TOPK; kk++) {
        double bvv2 = v[0];
        int bi = lane * 4;
#pragma unroll
        for (int j = 1; j < 4; j++)
          if (v[j] > bvv2) { bvv2 = v[j]; bi = lane * 4 + j; }
#pragma unroll
        for (int d = 1; d <= 32; d <<= 1) {
          double ov = __shfl_xor(bvv2, d);
          int oi = __shfl_xor(bi, d);
          if (ov > bvv2 || (ov == bvv2 && oi < bi)) { bvv2 = ov; bi = oi; }
        }
        selE[kk] = bi;
        int ol = bi >> 2, oj = bi & 3;
        double cand = (oj == 0) ? s[0] : (oj == 1) ? s[1] : (oj == 2) ? s[2] : s[3];
        selS[kk] = __shfl(cand, ol);
#pragma unroll
        for (int j = 0; j < 4; j++)
          if (lane == ol && j == oj) v[j] = NEG;
      }

      double denom = 1e-20;
#pragma unroll
      for (int kk = 0; kk < TOPK; kk++) denom += selS[kk];
      double scale = 2.5 / denom;

      if (lane == 0) {
        float4 o;
        o.x = (float)(selS[0] * scale); o.y = (float)(selS[1] * scale);
        o.z = (float)(selS[2] * scale); o.w = (float)(selS[3] * scale);
        *reinterpret_cast<float4*>(out_scores + (size_t)t * TOPK) = o;
        o.x = (float)(selS[4] * scale); o.y = (float)(selS[5] * scale);
        o.z = (float)(selS[6] * scale); o.w = (float)(selS[7] * scale);
        *reinterpret_cast<float4*>(out_scores + (size_t)t * TOPK + 4) = o;
        float4 e;
        e.x = (float)selE[0]; e.y = (float)selE[1];
        e.z = (float)selE[2]; e.w = (float)selE[3];
        *reinterpret_cast<float4*>(out_sel + (size_t)t * TOPK) = e;
        e.x = (float)selE[4]; e.y = (float)selE[5];
        e.z = (float)selE[6]; e.w = (float)selE[7];
        *reinterpret_cast<float4*>(out_sel + (size_t)t * TOPK + 4) = e;
#pragma unroll
        for (int kk = 0; kk < TOPK; kk++)
          atomicAdd(&out_counts[selE[kk]], 1.0f);
      }
    }
    __syncthreads();
  }
}

extern "C" void kernel_launch(void* const* d_in, const int* in_sizes, int n_in,
                              void* d_out, int out_size, void* d_ws, size_t ws_size,
                              hipStream_t stream) {
  const float* x = (const float*)d_in[0];
  const float* w = (const float*)d_in[1];
  const float* bias = (const float*)d_in[2];
  float* out = (float*)d_out;
  float* out_scores = out;
  float* out_sel = out + T_TOK * TOPK;
  float* out_counts = out + 2 * T_TOK * TOPK;

  char* ws = (char*)d_ws;
  float* scores = (float*)ws;                                   // 16 MiB
  _Float16* wh = (_Float16*)(ws + (size_t)16 * 1024 * 1024);    // 1 MiB
  _Float16* wlo = (_Float16*)(ws + (size_t)17 * 1024 * 1024);   // 1 MiB
  int* wl_count = (int*)(ws + (size_t)18 * 1024 * 1024);
  int* wlist = wl_count + 16;
  double* scG = (double*)(ws + (size_t)19 * 1024 * 1024);       // <= 12.6 MiB

  prep<<<2048, 256, 0, stream>>>(w, wh, wlo, out_counts, wl_count);
  gate_gemm_mfma<<<512, 256, 0, stream>>>(x, wh, wlo, scores);
  router_serial<<<T_TOK / 64, 64, 0, stream>>>(scores, bias, out_scores,
                                               out_sel, out_counts, wl_count,
                                               wlist);
  fixup_logits<<<2048, 256, 0, stream>>>(x, w, wl_count, wlist, scG);
  fixup_select<<<2048, 256, 0, stream>>>(scG, x, w, bias, out_scores, out_sel,
                                         out_counts, wl_count, wlist);
}

// Round 15
// 185.580 us; speedup vs baseline: 19.9672x; 19.9672x over previous
//
#include <hip/hip_runtime.h>
#include <math.h>

#define T_TOK 16384
#define DDIM 2048
#define NEXP 256
#define TOPK 8
#define NLIM 4
#define CAPN 6144

constexpr float EPSC = 1e-5f;         // certified score-space error bound
constexpr float SCL = 1.f / 4096.f;   // undo x*16, w*256 scaling

typedef _Float16 half4v __attribute__((ext_vector_type(4)));
typedef _Float16 half8v __attribute__((ext_vector_type(8)));
typedef float f32x4 __attribute__((ext_vector_type(4)));

// ---------------- K0: convert w to fp16 hi/lo + init counts/worklist -------
__global__ __launch_bounds__(256) void prep(
    const float* __restrict__ w, _Float16* __restrict__ wh,
    _Float16* __restrict__ wlo, float* __restrict__ counts,
    int* __restrict__ wl_count) {
  int gid = blockIdx.x * 256 + threadIdx.x;
  float W = w[gid] * 256.f;
  _Float16 h = (_Float16)W;
  wh[gid] = h;
  wlo[gid] = (_Float16)(W - (float)h);
  if (blockIdx.x == 0) {
    counts[threadIdx.x] = 0.f;
    if (threadIdx.x == 0) *wl_count = 0;
  }
}

// --- K1: MFMA gate GEMM (r9 geometry) + STATIC 2-deep register prefetch ----
constexpr int BM = 64, BN = 128, BK = 64, NT = DDIM / BK;  // NT=32 (even)
__global__ __launch_bounds__(256) void gate_gemm_mfma(
    const float* __restrict__ x, const _Float16* __restrict__ wh,
    const _Float16* __restrict__ wlo, float* __restrict__ scores) {
  __shared__ _Float16 Ah[64][72], Al[64][72];
  __shared__ _Float16 Bh[128][72], Bl[128][72];
  const int tid = threadIdx.x;
  const int bid = blockIdx.x;
  const int mb = bid >> 1, nb = bid & 1;
  const int row0 = mb * BM, col0 = nb * BN;
  const int wave = tid >> 6, lane = tid & 63;
  const int m0 = (wave >> 1) * 32, n0 = (wave & 1) * 64;

  f32x4 acc[2][4];
#pragma unroll
  for (int i = 0; i < 2; i++)
#pragma unroll
    for (int j = 0; j < 4; j++) acc[i][j] = (f32x4){0.f, 0.f, 0.f, 0.f};

  // two NAMED register staging sets (all indices compile-time -> stay in VGPR)
  float4 ar0[4], ar1[4];
  half8v bh0[4], bl0[4], bh1[4], bl1[4];

  auto LOAD = [&](int t, float4 (&ar)[4], half8v (&bh)[4], half8v (&bl)[4]) {
    const int k0 = t * BK;
#pragma unroll
    for (int i = 0; i < 4; i++) {
      int f = i * 256 + tid;
      int r = f >> 4, c4 = (f & 15) << 2;
      ar[i] = *reinterpret_cast<const float4*>(
          x + (size_t)(row0 + r) * DDIM + k0 + c4);
    }
#pragma unroll
    for (int i = 0; i < 4; i++) {
      int f = i * 256 + tid;
      int r = f >> 3, k8 = (f & 7) << 3;
      size_t g = (size_t)(col0 + r) * DDIM + k0 + k8;
      bh[i] = *reinterpret_cast<const half8v*>(wh + g);
      bl[i] = *reinterpret_cast<const half8v*>(wlo + g);
    }
  };
  auto WRITE = [&](float4 (&ar)[4], half8v (&bh)[4], half8v (&bl)[4]) {
#pragma unroll
    for (int i = 0; i < 4; i++) {
      int f = i * 256 + tid;
      int r = f >> 4, c4 = (f & 15) << 2;
      float4 v = ar[i];
      float X0 = v.x * 16.f, X1 = v.y * 16.f, X2 = v.z * 16.f, X3 = v.w * 16.f;
      _Float16 h0 = (_Float16)X0, h1 = (_Float16)X1;
      _Float16 h2 = (_Float16)X2, h3 = (_Float16)X3;
      half4v hv = {h0, h1, h2, h3};
      half4v lv = {(_Float16)(X0 - (float)h0), (_Float16)(X1 - (float)h1),
                   (_Float16)(X2 - (float)h2), (_Float16)(X3 - (float)h3)};
      *reinterpret_cast<half4v*>(&Ah[r][c4]) = hv;
      *reinterpret_cast<half4v*>(&Al[r][c4]) = lv;
    }
#pragma unroll
    for (int i = 0; i < 4; i++) {
      int f = i * 256 + tid;
      int r = f >> 3, k8 = (f & 7) << 3;
      *reinterpret_cast<half8v*>(&Bh[r][k8]) = bh[i];
      *reinterpret_cast<half8v*>(&Bl[r][k8]) = bl[i];
    }
  };
  auto COMPUTE = [&]() {
#pragma unroll
    for (int ks = 0; ks < 2; ks++) {
      const int koff = ks * 32 + (lane >> 4) * 8;
      half8v fah[2], fal[2], fbh[4], fbl[4];
#pragma unroll
      for (int mf = 0; mf < 2; mf++) {
        int r = m0 + mf * 16 + (lane & 15);
        fah[mf] = *reinterpret_cast<half8v*>(&Ah[r][koff]);
        fal[mf] = *reinterpret_cast<half8v*>(&Al[r][koff]);
      }
#pragma unroll
      for (int nf = 0; nf < 4; nf++) {
        int c = n0 + nf * 16 + (lane & 15);
        fbh[nf] = *reinterpret_cast<half8v*>(&Bh[c][koff]);
        fbl[nf] = *reinterpret_cast<half8v*>(&Bl[c][koff]);
      }
#pragma unroll
      for (int mf = 0; mf < 2; mf++)
#pragma unroll
        for (int nf = 0; nf < 4; nf++) {
          acc[mf][nf] = __builtin_amdgcn_mfma_f32_16x16x32_f16(
              fah[mf], fbh[nf], acc[mf][nf], 0, 0, 0);
          acc[mf][nf] = __builtin_amdgcn_mfma_f32_16x16x32_f16(
              fah[mf], fbl[nf], acc[mf][nf], 0, 0, 0);
          acc[mf][nf] = __builtin_amdgcn_mfma_f32_16x16x32_f16(
              fal[mf], fbh[nf], acc[mf][nf], 0, 0, 0);
        }
    }
  };

  LOAD(0, ar0, bh0, bl0);
  LOAD(1, ar1, bh1, bl1);
  for (int t = 0; t < NT; t += 2) {
    // tile t (slot 0): loads issued 2 iterations ago -> vmcnt wait is a no-op
    WRITE(ar0, bh0, bl0);
    __syncthreads();
    if (t + 2 < NT) LOAD(t + 2, ar0, bh0, bl0);
    COMPUTE();
    __syncthreads();
    // tile t+1 (slot 1)
    WRITE(ar1, bh1, bl1);
    __syncthreads();
    if (t + 3 < NT) LOAD(t + 3, ar1, bh1, bl1);
    COMPUTE();
    __syncthreads();
  }
  // epilogue: sigmoid, plain stores
#pragma unroll
  for (int mf = 0; mf < 2; mf++)
#pragma unroll
    for (int nf = 0; nf < 4; nf++)
#pragma unroll
      for (int r = 0; r < 4; r++) {
        int row = row0 + m0 + mf * 16 + (lane >> 4) * 4 + r;
        int col = col0 + n0 + nf * 16 + (lane & 15);
        float sv = 1.f / (1.f + expf(-acc[mf][nf][r] * SCL));
        scores[(size_t)row * NEXP + col] = sv;
      }
}

// -------- K2: serial-lane router: one lane per token, u64-key top-9 --------
__global__ __launch_bounds__(64) void router_serial(
    const float* __restrict__ scores, const float* __restrict__ bias,
    float* __restrict__ out_scores, float* __restrict__ out_sel,
    float* __restrict__ out_counts, int* __restrict__ wl_count,
    int* __restrict__ wlist) {
  __shared__ float S[64][257];  // biased scores; stride 257 -> 2-way banks
  __shared__ float BS[256];
  __shared__ int hist[256];
  const int lane = threadIdx.x;
  const int t0 = blockIdx.x * 64;

#pragma unroll
  for (int i = 0; i < 4; i++) {
    hist[i * 64 + lane] = 0;
    BS[i * 64 + lane] = bias[i * 64 + lane];
  }
  float4 bv = *reinterpret_cast<const float4*>(bias + lane * 4);
  for (int r = 0; r < 64; r++) {
    float4 v = *reinterpret_cast<const float4*>(
        scores + (size_t)(t0 + r) * NEXP + lane * 4);
    S[r][lane * 4 + 0] = v.x + bv.x;
    S[r][lane * 4 + 1] = v.y + bv.y;
    S[r][lane * 4 + 2] = v.z + bv.z;
    S[r][lane * 4 + 3] = v.w + bv.w;
  }
  __syncthreads();

  const float* Srow = S[lane];
  const int t = t0 + lane;

  // phase A: per-group top-2 sums
  float gsArr[8];
#pragma unroll
  for (int g = 0; g < 8; g++) {
    float m1 = -INFINITY, m2 = -INFINITY;
#pragma unroll 4
    for (int k = 0; k < 32; k++) {
      float c = Srow[g * 32 + k];
      float mx = fmaxf(m1, c);
      m2 = fmaxf(m2, fminf(m1, c));
      m1 = mx;
    }
    gsArr[g] = m1 + m2;
  }

  // group ranks -> kept nibble-pack, 4th/5th margin
  int kgpack = 0;
  float v4 = 0.f, v5 = 0.f;
#pragma unroll
  for (int g = 7; g >= 0; g--) {
    int rk = 0;
#pragma unroll
    for (int h = 0; h < 8; h++)
      rk += (gsArr[h] > gsArr[g]) || (gsArr[h] == gsArr[g] && h < g);
    if (rk < NLIM) kgpack = (kgpack << 4) | g;
    if (rk == 3) v4 = gsArr[g];
    if (rk == 4) v5 = gsArr[g];
  }
  bool flag = (v4 - v5) < 8.f * EPSC;

  // phase B: branchless 9-slot insertion over 128 eligible, u64 keys
  unsigned long long L[9];
#pragma unroll
  for (int i = 0; i < 9; i++) L[i] = 0ULL;
#pragma unroll
  for (int gi = 0; gi < 4; gi++) {
    const int cb = ((kgpack >> (gi * 4)) & 15) * 32;
#pragma unroll 2
    for (int k = 0; k < 32; k++) {
      float c = Srow[cb + k];
      unsigned int bits = __float_as_uint(c + 1.0f);
      unsigned long long key =
          ((unsigned long long)bits << 8) | (unsigned)(255 - (cb + k));
#pragma unroll
      for (int sl = 0; sl < 9; sl++) {
        bool gt = key > L[sl];
        unsigned long long nl = gt ? key : L[sl];
        key = gt ? L[sl] : key;
        L[sl] = nl;
      }
    }
  }

  int selE[9];
  float cval[9];
#pragma unroll
  for (int i = 0; i < 9; i++) {
    selE[i] = 255 - (int)(L[i] & 0xFFULL);
    cval[i] = __uint_as_float((unsigned)(L[i] >> 8)) - 1.0f;
  }
#pragma unroll
  for (int i = 0; i < 8; i++)
    flag = flag || ((cval[i] - cval[i + 1]) < 2.f * EPSC);

  if (!flag) {
    float s[8];
    float denom = 1e-20f;
#pragma unroll
    for (int i = 0; i < 8; i++) {
      s[i] = Srow[selE[i]] - BS[selE[i]];
      denom += s[i];
    }
    float scale = 2.5f / denom;
    float4 o0 = {s[0] * scale, s[1] * scale, s[2] * scale, s[3] * scale};
    float4 o1 = {s[4] * scale, s[5] * scale, s[6] * scale, s[7] * scale};
    *reinterpret_cast<float4*>(out_scores + (size_t)t * TOPK) = o0;
    *reinterpret_cast<float4*>(out_scores + (size_t)t * TOPK + 4) = o1;
    float4 e0 = {(float)selE[0], (float)selE[1], (float)selE[2], (float)selE[3]};
    float4 e1 = {(float)selE[4], (float)selE[5], (float)selE[6], (float)selE[7]};
    *reinterpret_cast<float4*>(out_sel + (size_t)t * TOPK) = e0;
    *reinterpret_cast<float4*>(out_sel + (size_t)t * TOPK + 4) = e1;
#pragma unroll
    for (int i = 0; i < 8; i++) atomicAdd(&hist[selE[i]], 1);
  } else {
    int i = atomicAdd(wl_count, 1);
    wlist[i] = t;
  }
  __syncthreads();
#pragma unroll
  for (int i = 0; i < 4; i++) {
    int h = hist[i * 64 + lane];
    if (h) atomicAdd(&out_counts[i * 64 + lane], (float)h);
  }
}

// ---- K3a: f64 logits for flagged tokens; block = (token-quad, 16 experts) -
__global__ __launch_bounds__(256) void fixup_logits(
    const float* __restrict__ x, const float* __restrict__ w,
    const int* __restrict__ wl_count, const int* __restrict__ wlist,
    double* __restrict__ scG) {
  __shared__ float xs[4][DDIM];  // 32 KB
  __shared__ int toks[4];
  const int n = min(*wl_count, CAPN);
  const int nq = (n + 3) >> 2;
  const int nwork = nq * 16;
  const int tid = threadIdx.x;
  const int wv = tid >> 6, lane = tid & 63;

  for (int wk = blockIdx.x; wk < nwork; wk += gridDim.x) {
    const int q = wk >> 4, ec = wk & 15;
    __syncthreads();
    if (tid < 4) {
      int idx = q * 4 + tid;
      toks[tid] = wlist[idx < n ? idx : (n - 1)];
    }
    __syncthreads();
    for (int i = tid; i < 4 * 512; i += 256) {
      int tk = i >> 9, off = i & 511;
      reinterpret_cast<float4*>(xs[tk])[off] =
          reinterpret_cast<const float4*>(x + (size_t)toks[tk] * DDIM)[off];
    }
    __syncthreads();

#pragma unroll 1
    for (int ei = 0; ei < 4; ei++) {
      const int e = ec * 16 + wv * 4 + ei;
      const float* wr = w + (size_t)e * DDIM + lane * 4;
      float4 wreg[8];
#pragma unroll
      for (int j = 0; j < 8; j++)
        wreg[j] = *reinterpret_cast<const float4*>(wr + j * 256);
      double p0 = 0, p1 = 0, p2 = 0, p3 = 0;
#pragma unroll
      for (int j = 0; j < 8; j++) {
        const int k = j * 256 + lane * 4;
        float4 wv4 = wreg[j];
        float4 x0 = *reinterpret_cast<const float4*>(&xs[0][k]);
        float4 x1 = *reinterpret_cast<const float4*>(&xs[1][k]);
        float4 x2 = *reinterpret_cast<const float4*>(&xs[2][k]);
        float4 x3 = *reinterpret_cast<const float4*>(&xs[3][k]);
        p0 = fma((double)x0.x, (double)wv4.x, p0);
        p0 = fma((double)x0.y, (double)wv4.y, p0);
        p0 = fma((double)x0.z, (double)wv4.z, p0);
        p0 = fma((double)x0.w, (double)wv4.w, p0);
        p1 = fma((double)x1.x, (double)wv4.x, p1);
        p1 = fma((double)x1.y, (double)wv4.y, p1);
        p1 = fma((double)x1.z, (double)wv4.z, p1);
        p1 = fma((double)x1.w, (double)wv4.w, p1);
        p2 = fma((double)x2.x, (double)wv4.x, p2);
        p2 = fma((double)x2.y, (double)wv4.y, p2);
        p2 = fma((double)x2.z, (double)wv4.z, p2);
        p2 = fma((double)x2.w, (double)wv4.w, p2);
        p3 = fma((double)x3.x, (double)wv4.x, p3);
        p3 = fma((double)x3.y, (double)wv4.y, p3);
        p3 = fma((double)x3.z, (double)wv4.z, p3);
        p3 = fma((double)x3.w, (double)wv4.w, p3);
      }
#pragma unroll
      for (int d = 1; d <= 32; d <<= 1) {
        p0 += __shfl_xor(p0, d);
        p1 += __shfl_xor(p1, d);
        p2 += __shfl_xor(p2, d);
        p3 += __shfl_xor(p3, d);
      }
      if (lane == 0) {
        const int it0 = q * 4;
        if (it0 + 0 < n) scG[(size_t)(it0 + 0) * NEXP + e] = 1.0 / (1.0 + exp(-p0));
        if (it0 + 1 < n) scG[(size_t)(it0 + 1) * NEXP + e] = 1.0 / (1.0 + exp(-p1));
        if (it0 + 2 < n) scG[(size_t)(it0 + 2) * NEXP + e] = 1.0 / (1.0 + exp(-p2));
        if (it0 + 3 < n) scG[(size_t)(it0 + 3) * NEXP + e] = 1.0 / (1.0 + exp(-p3));
      }
    }
  }
}

// ---- K3b: exact f64 selection per flagged token (reads scG) ---------------
__global__ __launch_bounds__(256) void fixup_select(
    const double* __restrict__ scG, const float* __restrict__ x,
    const float* __restrict__ w, const float* __restrict__ bias,
    float* __restrict__ out_scores, float* __restrict__ out_sel,
    float* __restrict__ out_counts, const int* __restrict__ wl_count,
    const int* __restrict__ wlist) {
  __shared__ double sc[NEXP];
  const int n = *wl_count;
  const int tid = threadIdx.x;
  const int wv = tid >> 6, lane = tid & 63;

  for (int it = blockIdx.x; it < n; it += gridDim.x) {
    const int t = wlist[it];
    __syncthreads();
    if (it < CAPN) {
      sc[tid] = scG[(size_t)it * NEXP + tid];
    } else {
      // fallback (never taken at observed n): compute inline
      const float* xrow = x + (size_t)t * DDIM + lane * 8;
      float4 xr[4][2];
#pragma unroll
      for (int p = 0; p < 4; p++) {
        xr[p][0] = *reinterpret_cast<const float4*>(xrow + p * 512);
        xr[p][1] = *reinterpret_cast<const float4*>(xrow + p * 512 + 4);
      }
      double myLogit = 0.0;
      for (int e = 0; e < 64; e++) {
        const float* wr = w + (size_t)(wv * 64 + e) * DDIM + lane * 8;
        double a0 = 0, a1 = 0;
#pragma unroll
        for (int p = 0; p < 4; p++) {
          float4 w0 = *reinterpret_cast<const float4*>(wr + p * 512);
          float4 w1 = *reinterpret_cast<const float4*>(wr + p * 512 + 4);
          a0 = fma((double)xr[p][0].x, (double)w0.x, a0);
          a1 = fma((double)xr[p][0].y, (double)w0.y, a1);
          a0 = fma((double)xr[p][0].z, (double)w0.z, a0);
          a1 = fma((double)xr[p][0].w, (double)w0.w, a1);
          a0 = fma((double)xr[p][1].x, (double)w1.x, a0);
          a1 = fma((double)xr[p][1].y, (double)w1.y, a1);
          a0 = fma((double)xr[p][1].z, (double)w1.z, a0);
          a1 = fma((double)xr[p][1].w, (double)w1.w, a1);
        }
        double tot = a0 + a1;
#pragma unroll
        for (int d = 1; d <= 32; d <<= 1) tot += __shfl_xor(tot, d);
        if (lane == e) myLogit = tot;
      }
      sc[wv * 64 + lane] = 1.0 / (1.0 + exp(-myLogit));
    }
    __syncthreads();

    if (tid < 64) {
      double s[4], c[4];
      s[0] = sc[lane * 4 + 0]; s[1] = sc[lane * 4 + 1];
      s[2] = sc[lane * 4 + 2]; s[3] = sc[lane * 4 + 3];
      float4 bvv = *reinterpret_cast<const float4*>(bias + lane * 4);
      c[0] = s[0] + (double)bvv.x; c[1] = s[1] + (double)bvv.y;
      c[2] = s[2] + (double)bvv.z; c[3] = s[3] + (double)bvv.w;

      double h1 = fmax(c[0], c[1]), l1 = fmin(c[0], c[1]);
      double h2 = fmax(c[2], c[3]), l2 = fmin(c[2], c[3]);
      double m1 = fmax(h1, h2);
      double m2 = fmax(fmin(h1, h2), fmax(l1, l2));
#pragma unroll
      for (int d = 1; d <= 4; d <<= 1) {
        double om1 = __shfl_xor(m1, d);
        double om2 = __shfl_xor(m2, d);
        double n1 = fmax(m1, om1);
        double n2 = fmax(fmin(m1, om1), fmax(m2, om2));
        m1 = n1; m2 = n2;
      }
      double gscore = m1 + m2;
      double gsv[8];
#pragma unroll
      for (int g = 0; g < 8; g++) gsv[g] = __shfl(gscore, g * 8);
      const int gme = lane >> 3;
      int rank = 0;
#pragma unroll
      for (int h = 0; h < 8; h++)
        rank += (gsv[h] > gsv[gme]) || (gsv[h] == gsv[gme] && h < gme);
      const bool keep = rank < NLIM;

      const double NEG = -HUGE_VAL;
      double v[4];
#pragma unroll
      for (int j = 0; j < 4; j++) v[j] = keep ? c[j] : NEG;

      double selS[TOPK];
      int selE[TOPK];
#pragma unroll
      for (int kk = 0; kk < TOPK; kk++) {
        double bvv2 = v[0];
        int bi = lane * 4;
#pragma unroll
        for (int j = 1; j < 4; j++)
          if (v[j] > bvv2) { bvv2 = v[j]; bi = lane * 4 + j; }
#pragma unroll
        for (int d = 1; d <= 32; d <<= 1) {
          double ov = __shfl_xor(bvv2, d);
          int oi = __shfl_xor(bi, d);
          if (ov > bvv2 || (ov == bvv2 && oi < bi)) { bvv2 = ov; bi = oi; }
        }
        selE[kk] = bi;
        int ol = bi >> 2, oj = bi & 3;
        double cand = (oj == 0) ? s[0] : (oj == 1) ? s[1] : (oj == 2) ? s[2] : s[3];
        selS[kk] = __shfl(cand, ol);
#pragma unroll
        for (int j = 0; j < 4; j++)
          if (lane == ol && j == oj) v[j] = NEG;
      }

      double denom = 1e-20;
#pragma unroll
      for (int kk = 0; kk < TOPK; kk++) denom += selS[kk];
      double scale = 2.5 / denom;

      if (lane == 0) {
        float4 o;
        o.x = (float)(selS[0] * scale); o.y = (float)(selS[1] * scale);
        o.z = (float)(selS[2] * scale); o.w = (float)(selS[3] * scale);
        *reinterpret_cast<float4*>(out_scores + (size_t)t * TOPK) = o;
        o.x = (float)(selS[4] * scale); o.y = (float)(selS[5] * scale);
        o.z = (float)(selS[6] * scale); o.w = (float)(selS[7] * scale);
        *reinterpret_cast<float4*>(out_scores + (size_t)t * TOPK + 4) = o;
        float4 e;
        e.x = (float)selE[0]; e.y = (float)selE[1];
        e.z = (float)selE[2]; e.w = (float)selE[3];
        *reinterpret_cast<float4*>(out_sel + (size_t)t * TOPK) = e;
        e.x = (float)selE[4]; e.y = (float)selE[5];
        e.z = (float)selE[6]; e.w = (float)selE[7];
        *reinterpret_cast<float4*>(out_sel + (size_t)t * TOPK + 4) = e;
#pragma unroll
        for (int kk = 0; kk < TOPK; kk++)
          atomicAdd(&out_counts[selE[kk]], 1.0f);
      }
    }
    __syncthreads();
  }
}

extern "C" void kernel_launch(void* const* d_in, const int* in_sizes, int n_in,
                              void* d_out, int out_size, void* d_ws, size_t ws_size,
                              hipStream_t stream) {
  const float* x = (const float*)d_in[0];
  const float* w = (const float*)d_in[1];
  const float* bias = (const float*)d_in[2];
  float* out = (float*)d_out;
  float* out_scores = out;
  float* out_sel = out + T_TOK * TOPK;
  float* out_counts = out + 2 * T_TOK * TOPK;

  char* ws = (char*)d_ws;
  float* scores = (float*)ws;                                   // 16 MiB
  _Float16* wh = (_Float16*)(ws + (size_t)16 * 1024 * 1024);    // 1 MiB
  _Float16* wlo = (_Float16*)(ws + (size_t)17 * 1024 * 1024);   // 1 MiB
  int* wl_count = (int*)(ws + (size_t)18 * 1024 * 1024);
  int* wlist = wl_count + 16;
  double* scG = (double*)(ws + (size_t)19 * 1024 * 1024);       // <= 12.6 MiB

  prep<<<2048, 256, 0, stream>>>(w, wh, wlo, out_counts, wl_count);
  gate_gemm_mfma<<<512, 256, 0, stream>>>(x, wh, wlo, scores);
  router_serial<<<T_TOK / 64, 64, 0, stream>>>(scores, bias, out_scores,
                                               out_sel, out_counts, wl_count,
                                               wlist);
  fixup_logits<<<2048, 256, 0, stream>>>(x, w, wl_count, wlist, scG);
  fixup_select<<<2048, 256, 0, stream>>>(scG, x, w, bias, out_scores, out_sel,
                                         out_counts, wl_count, wlist);
}

// Round 16
// 159.242 us; speedup vs baseline: 23.2697x; 1.1654x over previous
//
#include <hip/hip_runtime.h>
#include <math.h>

#define T_TOK 16384
#define DDIM 2048
#define NEXP 256
#define TOPK 8
#define NLIM 4
#define CAPN 6144

constexpr float EPSC = 1e-5f;         // certified score-space error bound
constexpr float SCL = 1.f / 4096.f;   // undo x*16, w*256 scaling

typedef _Float16 half4v __attribute__((ext_vector_type(4)));
typedef _Float16 half8v __attribute__((ext_vector_type(8)));
typedef float f32x4 __attribute__((ext_vector_type(4)));

// ---------------- K0: convert w to fp16 hi/lo + init counts/worklist -------
__global__ __launch_bounds__(256) void prep(
    const float* __restrict__ w, _Float16* __restrict__ wh,
    _Float16* __restrict__ wlo, float* __restrict__ counts,
    int* __restrict__ wl_count) {
  int gid = blockIdx.x * 256 + threadIdx.x;
  float W = w[gid] * 256.f;
  _Float16 h = (_Float16)W;
  wh[gid] = h;
  wlo[gid] = (_Float16)(W - (float)h);
  if (blockIdx.x == 0) {
    counts[threadIdx.x] = 0.f;
    if (threadIdx.x == 0) *wl_count = 0;
  }
}

// --- K1: MFMA gate GEMM — round-9 geometry (measured 92.6 us) + XCD swizzle
constexpr int BM = 64, BN = 128, BK = 64, NT = DDIM / BK;  // NT=32
__global__ __launch_bounds__(256) void gate_gemm_mfma(
    const float* __restrict__ x, const _Float16* __restrict__ wh,
    const _Float16* __restrict__ wlo, float* __restrict__ scores) {
  __shared__ _Float16 Ah[64][72], Al[64][72];
  __shared__ _Float16 Bh[128][72], Bl[128][72];
  const int tid = threadIdx.x;
  // bijective XCD swizzle (512 blocks, 64/XCD), n-fast pairing for A reuse
  const int bid = blockIdx.x;
  const int swz = (bid & 7) * 64 + (bid >> 3);
  const int mb = swz >> 1, nb = swz & 1;
  const int row0 = mb * BM, col0 = nb * BN;
  const int wave = tid >> 6, lane = tid & 63;
  const int m0 = (wave >> 1) * 32, n0 = (wave & 1) * 64;

  f32x4 acc[2][4];
#pragma unroll
  for (int i = 0; i < 2; i++)
#pragma unroll
    for (int j = 0; j < 4; j++) acc[i][j] = (f32x4){0.f, 0.f, 0.f, 0.f};

  float4 ar[4];
  half8v brh[4], brl[4];

  auto LOADT = [&](int t) {
    const int k0 = t * BK;
#pragma unroll
    for (int i = 0; i < 4; i++) {
      int f = i * 256 + tid;
      int r = f >> 4, c4 = (f & 15) << 2;
      ar[i] = *reinterpret_cast<const float4*>(
          x + (size_t)(row0 + r) * DDIM + k0 + c4);
    }
#pragma unroll
    for (int i = 0; i < 4; i++) {
      int f = i * 256 + tid;
      int r = f >> 3, k8 = (f & 7) << 3;
      size_t g = (size_t)(col0 + r) * DDIM + k0 + k8;
      brh[i] = *reinterpret_cast<const half8v*>(wh + g);
      brl[i] = *reinterpret_cast<const half8v*>(wlo + g);
    }
  };
  auto WRITET = [&]() {
#pragma unroll
    for (int i = 0; i < 4; i++) {
      int f = i * 256 + tid;
      int r = f >> 4, c4 = (f & 15) << 2;
      float4 v = ar[i];
      float X0 = v.x * 16.f, X1 = v.y * 16.f, X2 = v.z * 16.f, X3 = v.w * 16.f;
      _Float16 h0 = (_Float16)X0, h1 = (_Float16)X1;
      _Float16 h2 = (_Float16)X2, h3 = (_Float16)X3;
      half4v hv = {h0, h1, h2, h3};
      half4v lv = {(_Float16)(X0 - (float)h0), (_Float16)(X1 - (float)h1),
                   (_Float16)(X2 - (float)h2), (_Float16)(X3 - (float)h3)};
      *reinterpret_cast<half4v*>(&Ah[r][c4]) = hv;
      *reinterpret_cast<half4v*>(&Al[r][c4]) = lv;
    }
#pragma unroll
    for (int i = 0; i < 4; i++) {
      int f = i * 256 + tid;
      int r = f >> 3, k8 = (f & 7) << 3;
      *reinterpret_cast<half8v*>(&Bh[r][k8]) = brh[i];
      *reinterpret_cast<half8v*>(&Bl[r][k8]) = brl[i];
    }
  };

  LOADT(0);
  for (int t = 0; t < NT; t++) {
    WRITET();
    __syncthreads();
    if (t + 1 < NT) LOADT(t + 1);  // next tile in flight under compute
#pragma unroll
    for (int ks = 0; ks < 2; ks++) {
      const int koff = ks * 32 + (lane >> 4) * 8;
      half8v ah[2], al[2], bh[4], bl[4];
#pragma unroll
      for (int mf = 0; mf < 2; mf++) {
        int r = m0 + mf * 16 + (lane & 15);
        ah[mf] = *reinterpret_cast<half8v*>(&Ah[r][koff]);
        al[mf] = *reinterpret_cast<half8v*>(&Al[r][koff]);
      }
#pragma unroll
      for (int nf = 0; nf < 4; nf++) {
        int c = n0 + nf * 16 + (lane & 15);
        bh[nf] = *reinterpret_cast<half8v*>(&Bh[c][koff]);
        bl[nf] = *reinterpret_cast<half8v*>(&Bl[c][koff]);
      }
#pragma unroll
      for (int mf = 0; mf < 2; mf++)
#pragma unroll
        for (int nf = 0; nf < 4; nf++) {
          acc[mf][nf] = __builtin_amdgcn_mfma_f32_16x16x32_f16(
              ah[mf], bh[nf], acc[mf][nf], 0, 0, 0);
          acc[mf][nf] = __builtin_amdgcn_mfma_f32_16x16x32_f16(
              ah[mf], bl[nf], acc[mf][nf], 0, 0, 0);
          acc[mf][nf] = __builtin_amdgcn_mfma_f32_16x16x32_f16(
              al[mf], bh[nf], acc[mf][nf], 0, 0, 0);
        }
    }
    __syncthreads();
  }
  // epilogue: sigmoid, plain stores
#pragma unroll
  for (int mf = 0; mf < 2; mf++)
#pragma unroll
    for (int nf = 0; nf < 4; nf++)
#pragma unroll
      for (int r = 0; r < 4; r++) {
        int row = row0 + m0 + mf * 16 + (lane >> 4) * 4 + r;
        int col = col0 + n0 + nf * 16 + (lane & 15);
        float sv = 1.f / (1.f + expf(-acc[mf][nf][r] * SCL));
        scores[(size_t)row * NEXP + col] = sv;
      }
}

// -------- K2: serial-lane router: one lane per token, u64-key top-9 --------
__global__ __launch_bounds__(64) void router_serial(
    const float* __restrict__ scores, const float* __restrict__ bias,
    float* __restrict__ out_scores, float* __restrict__ out_sel,
    float* __restrict__ out_counts, int* __restrict__ wl_count,
    int* __restrict__ wlist) {
  __shared__ float S[64][257];  // biased scores; stride 257 -> 2-way banks
  __shared__ float BS[256];
  __shared__ int hist[256];
  const int lane = threadIdx.x;
  const int t0 = blockIdx.x * 64;

#pragma unroll
  for (int i = 0; i < 4; i++) {
    hist[i * 64 + lane] = 0;
    BS[i * 64 + lane] = bias[i * 64 + lane];
  }
  float4 bv = *reinterpret_cast<const float4*>(bias + lane * 4);
  for (int r = 0; r < 64; r++) {
    float4 v = *reinterpret_cast<const float4*>(
        scores + (size_t)(t0 + r) * NEXP + lane * 4);
    S[r][lane * 4 + 0] = v.x + bv.x;
    S[r][lane * 4 + 1] = v.y + bv.y;
    S[r][lane * 4 + 2] = v.z + bv.z;
    S[r][lane * 4 + 3] = v.w + bv.w;
  }
  __syncthreads();

  const float* Srow = S[lane];
  const int t = t0 + lane;

  // phase A: per-group top-2 sums
  float gsArr[8];
#pragma unroll
  for (int g = 0; g < 8; g++) {
    float m1 = -INFINITY, m2 = -INFINITY;
#pragma unroll 4
    for (int k = 0; k < 32; k++) {
      float c = Srow[g * 32 + k];
      float mx = fmaxf(m1, c);
      m2 = fmaxf(m2, fminf(m1, c));
      m1 = mx;
    }
    gsArr[g] = m1 + m2;
  }

  // group ranks -> kept nibble-pack, 4th/5th margin
  int kgpack = 0;
  float v4 = 0.f, v5 = 0.f;
#pragma unroll
  for (int g = 7; g >= 0; g--) {
    int rk = 0;
#pragma unroll
    for (int h = 0; h < 8; h++)
      rk += (gsArr[h] > gsArr[g]) || (gsArr[h] == gsArr[g] && h < g);
    if (rk < NLIM) kgpack = (kgpack << 4) | g;
    if (rk == 3) v4 = gsArr[g];
    if (rk == 4) v5 = gsArr[g];
  }
  bool flag = (v4 - v5) < 8.f * EPSC;

  // phase B: branchless 9-slot insertion over 128 eligible, u64 keys
  unsigned long long L[9];
#pragma unroll
  for (int i = 0; i < 9; i++) L[i] = 0ULL;
#pragma unroll
  for (int gi = 0; gi < 4; gi++) {
    const int cb = ((kgpack >> (gi * 4)) & 15) * 32;
#pragma unroll 2
    for (int k = 0; k < 32; k++) {
      float c = Srow[cb + k];
      unsigned int bits = __float_as_uint(c + 1.0f);
      unsigned long long key =
          ((unsigned long long)bits << 8) | (unsigned)(255 - (cb + k));
#pragma unroll
      for (int sl = 0; sl < 9; sl++) {
        bool gt = key > L[sl];
        unsigned long long nl = gt ? key : L[sl];
        key = gt ? L[sl] : key;
        L[sl] = nl;
      }
    }
  }

  int selE[9];
  float cval[9];
#pragma unroll
  for (int i = 0; i < 9; i++) {
    selE[i] = 255 - (int)(L[i] & 0xFFULL);
    cval[i] = __uint_as_float((unsigned)(L[i] >> 8)) - 1.0f;
  }
#pragma unroll
  for (int i = 0; i < 8; i++)
    flag = flag || ((cval[i] - cval[i + 1]) < 2.f * EPSC);

  if (!flag) {
    float s[8];
    float denom = 1e-20f;
#pragma unroll
    for (int i = 0; i < 8; i++) {
      s[i] = Srow[selE[i]] - BS[selE[i]];
      denom += s[i];
    }
    float scale = 2.5f / denom;
    float4 o0 = {s[0] * scale, s[1] * scale, s[2] * scale, s[3] * scale};
    float4 o1 = {s[4] * scale, s[5] * scale, s[6] * scale, s[7] * scale};
    *reinterpret_cast<float4*>(out_scores + (size_t)t * TOPK) = o0;
    *reinterpret_cast<float4*>(out_scores + (size_t)t * TOPK + 4) = o1;
    float4 e0 = {(float)selE[0], (float)selE[1], (float)selE[2], (float)selE[3]};
    float4 e1 = {(float)selE[4], (float)selE[5], (float)selE[6], (float)selE[7]};
    *reinterpret_cast<float4*>(out_sel + (size_t)t * TOPK) = e0;
    *reinterpret_cast<float4*>(out_sel + (size_t)t * TOPK + 4) = e1;
#pragma unroll
    for (int i = 0; i < 8; i++) atomicAdd(&hist[selE[i]], 1);
  } else {
    int i = atomicAdd(wl_count, 1);
    wlist[i] = t;
  }
  __syncthreads();
#pragma unroll
  for (int i = 0; i < 4; i++) {
    int h = hist[i * 64 + lane];
    if (h) atomicAdd(&out_counts[i * 64 + lane], (float)h);
  }
}

// ---- K3a: f64 logits for flagged tokens; block = (token-quad, 16 experts) -
__global__ __launch_bounds__(256) void fixup_logits(
    const float* __restrict__ x, const float* __restrict__ w,
    const int* __restrict__ wl_count, const int* __restrict__ wlist,
    double* __restrict__ scG) {
  __shared__ float xs[4][DDIM];  // 32 KB
  __shared__ int toks[4];
  const int n = min(*wl_count, CAPN);
  const int nq = (n + 3) >> 2;
  const int nwork = nq * 16;
  const int tid = threadIdx.x;
  const int wv = tid >> 6, lane = tid & 63;

  for (int wk = blockIdx.x; wk < nwork; wk += gridDim.x) {
    const int q = wk >> 4, ec = wk & 15;
    __syncthreads();
    if (tid < 4) {
      int idx = q * 4 + tid;
      toks[tid] = wlist[idx < n ? idx : (n - 1)];
    }
    __syncthreads();
    for (int i = tid; i < 4 * 512; i += 256) {
      int tk = i >> 9, off = i & 511;
      reinterpret_cast<float4*>(xs[tk])[off] =
          reinterpret_cast<const float4*>(x + (size_t)toks[tk] * DDIM)[off];
    }
    __syncthreads();

#pragma unroll 1
    for (int ei = 0; ei < 4; ei++) {
      const int e = ec * 16 + wv * 4 + ei;
      const float* wr = w + (size_t)e * DDIM + lane * 4;
      float4 wreg[8];
#pragma unroll
      for (int j = 0; j < 8; j++)
        wreg[j] = *reinterpret_cast<const float4*>(wr + j * 256);
      double p0 = 0, p1 = 0, p2 = 0, p3 = 0;
#pragma unroll
      for (int j = 0; j < 8; j++) {
        const int k = j * 256 + lane * 4;
        float4 wv4 = wreg[j];
        float4 x0 = *reinterpret_cast<const float4*>(&xs[0][k]);
        float4 x1 = *reinterpret_cast<const float4*>(&xs[1][k]);
        float4 x2 = *reinterpret_cast<const float4*>(&xs[2][k]);
        float4 x3 = *reinterpret_cast<const float4*>(&xs[3][k]);
        p0 = fma((double)x0.x, (double)wv4.x, p0);
        p0 = fma((double)x0.y, (double)wv4.y, p0);
        p0 = fma((double)x0.z, (double)wv4.z, p0);
        p0 = fma((double)x0.w, (double)wv4.w, p0);
        p1 = fma((double)x1.x, (double)wv4.x, p1);
        p1 = fma((double)x1.y, (double)wv4.y, p1);
        p1 = fma((double)x1.z, (double)wv4.z, p1);
        p1 = fma((double)x1.w, (double)wv4.w, p1);
        p2 = fma((double)x2.x, (double)wv4.x, p2);
        p2 = fma((double)x2.y, (double)wv4.y, p2);
        p2 = fma((double)x2.z, (double)wv4.z, p2);
        p2 = fma((double)x2.w, (double)wv4.w, p2);
        p3 = fma((double)x3.x, (double)wv4.x, p3);
        p3 = fma((double)x3.y, (double)wv4.y, p3);
        p3 = fma((double)x3.z, (double)wv4.z, p3);
        p3 = fma((double)x3.w, (double)wv4.w, p3);
      }
#pragma unroll
      for (int d = 1; d <= 32; d <<= 1) {
        p0 += __shfl_xor(p0, d);
        p1 += __shfl_xor(p1, d);
        p2 += __shfl_xor(p2, d);
        p3 += __shfl_xor(p3, d);
      }
      if (lane == 0) {
        const int it0 = q * 4;
        if (it0 + 0 < n) scG[(size_t)(it0 + 0) * NEXP + e] = 1.0 / (1.0 + exp(-p0));
        if (it0 + 1 < n) scG[(size_t)(it0 + 1) * NEXP + e] = 1.0 / (1.0 + exp(-p1));
        if (it0 + 2 < n) scG[(size_t)(it0 + 2) * NEXP + e] = 1.0 / (1.0 + exp(-p2));
        if (it0 + 3 < n) scG[(size_t)(it0 + 3) * NEXP + e] = 1.0 / (1.0 + exp(-p3));
      }
    }
  }
}

// ---- K3b: exact f64 selection per flagged token (reads scG) ---------------
__global__ __launch_bounds__(256) void fixup_select(
    const double* __restrict__ scG, const float* __restrict__ x,
    const float* __restrict__ w, const float* __restrict__ bias,
    float* __restrict__ out_scores, float* __restrict__ out_sel,
    float* __restrict__ out_counts, const int* __restrict__ wl_count,
    const int* __restrict__ wlist) {
  __shared__ double sc[NEXP];
  const int n = *wl_count;
  const int tid = threadIdx.x;
  const int wv = tid >> 6, lane = tid & 63;

  for (int it = blockIdx.x; it < n; it += gridDim.x) {
    const int t = wlist[it];
    __syncthreads();
    if (it < CAPN) {
      sc[tid] = scG[(size_t)it * NEXP + tid];
    } else {
      // fallback (never taken at observed n): compute inline
      const float* xrow = x + (size_t)t * DDIM + lane * 8;
      float4 xr[4][2];
#pragma unroll
      for (int p = 0; p < 4; p++) {
        xr[p][0] = *reinterpret_cast<const float4*>(xrow + p * 512);
        xr[p][1] = *reinterpret_cast<const float4*>(xrow + p * 512 + 4);
      }
      double myLogit = 0.0;
      for (int e = 0; e < 64; e++) {
        const float* wr = w + (size_t)(wv * 64 + e) * DDIM + lane * 8;
        double a0 = 0, a1 = 0;
#pragma unroll
        for (int p = 0; p < 4; p++) {
          float4 w0 = *reinterpret_cast<const float4*>(wr + p * 512);
          float4 w1 = *reinterpret_cast<const float4*>(wr + p * 512 + 4);
          a0 = fma((double)xr[p][0].x, (double)w0.x, a0);
          a1 = fma((double)xr[p][0].y, (double)w0.y, a1);
          a0 = fma((double)xr[p][0].z, (double)w0.z, a0);
          a1 = fma((double)xr[p][0].w, (double)w0.w, a1);
          a0 = fma((double)xr[p][1].x, (double)w1.x, a0);
          a1 = fma((double)xr[p][1].y, (double)w1.y, a1);
          a0 = fma((double)xr[p][1].z, (double)w1.z, a0);
          a1 = fma((double)xr[p][1].w, (double)w1.w, a1);
        }
        double tot = a0 + a1;
#pragma unroll
        for (int d = 1; d <= 32; d <<= 1) tot += __shfl_xor(tot, d);
        if (lane == e) myLogit = tot;
      }
      sc[wv * 64 + lane] = 1.0 / (1.0 + exp(-myLogit));
    }
    __syncthreads();

    if (tid < 64) {
      double s[4], c[4];
      s[0] = sc[lane * 4 + 0]; s[1] = sc[lane * 4 + 1];
      s[2] = sc[lane * 4 + 2]; s[3] = sc[lane * 4 + 3];
      float4 bvv = *reinterpret_cast<const float4*>(bias + lane * 4);
      c[0] = s[0] + (double)bvv.x; c[1] = s[1] + (double)bvv.y;
      c[2] = s[2] + (double)bvv.z; c[3] = s[3] + (double)bvv.w;

      double h1 = fmax(c[0], c[1]), l1 = fmin(c[0], c[1]);
      double h2 = fmax(c[2], c[3]), l2 = fmin(c[2], c[3]);
      double m1 = fmax(h1, h2);
      double m2 = fmax(fmin(h1, h2), fmax(l1, l2));
#pragma unroll
      for (int d = 1; d <= 4; d <<= 1) {
        double om1 = __shfl_xor(m1, d);
        double om2 = __shfl_xor(m2, d);
        double n1 = fmax(m1, om1);
        double n2 = fmax(fmin(m1, om1), fmax(m2, om2));
        m1 = n1; m2 = n2;
      }
      double gscore = m1 + m2;
      double gsv[8];
#pragma unroll
      for (int g = 0; g < 8; g++) gsv[g] = __shfl(gscore, g * 8);
      const int gme = lane >> 3;
      int rank = 0;
#pragma unroll
      for (int h = 0; h < 8; h++)
        rank += (gsv[h] > gsv[gme]) || (gsv[h] == gsv[gme] && h < gme);
      const bool keep = rank < NLIM;

      const double NEG = -HUGE_VAL;
      double v[4];
#pragma unroll
      for (int j = 0; j < 4; j++) v[j] = keep ? c[j] : NEG;

      double selS[TOPK];
      int selE[TOPK];
#pragma unroll
      for (int kk = 0; kk < TOPK; kk++) {
        double bvv2 = v[0];
        int bi = lane * 4;
#pragma unroll
        for (int j = 1; j < 4; j++)
          if (v[j] > bvv2) { bvv2 = v[j]; bi = lane * 4 + j; }
#pragma unroll
        for (int d = 1; d <= 32; d <<= 1) {
          double ov = __shfl_xor(bvv2, d);
          int oi = __shfl_xor(bi, d);
          if (ov > bvv2 || (ov == bvv2 && oi < bi)) { bvv2 = ov; bi = oi; }
        }
        selE[kk] = bi;
        int ol = bi >> 2, oj = bi & 3;
        double cand = (oj == 0) ? s[0] : (oj == 1) ? s[1] : (oj == 2) ? s[2] : s[3];
        selS[kk] = __shfl(cand, ol);
#pragma unroll
        for (int j = 0; j < 4; j++)
          if (lane == ol && j == oj) v[j] = NEG;
      }

      double denom = 1e-20;
#pragma unroll
      for (int kk = 0; kk < TOPK; kk++) denom += selS[kk];
      double scale = 2.5 / denom;

      if (lane == 0) {
        float4 o;
        o.x = (float)(selS[0] * scale); o.y = (float)(selS[1] * scale);
        o.z = (float)(selS[2] * scale); o.w = (float)(selS[3] * scale);
        *reinterpret_cast<float4*>(out_scores + (size_t)t * TOPK) = o;
        o.x = (float)(selS[4] * scale); o.y = (float)(selS[5] * scale);
        o.z = (float)(selS[6] * scale); o.w = (float)(selS[7] * scale);
        *reinterpret_cast<float4*>(out_scores + (size_t)t * TOPK + 4) = o;
        float4 e;
        e.x = (float)selE[0]; e.y = (float)selE[1];
        e.z = (float)selE[2]; e.w = (float)selE[3];
        *reinterpret_cast<float4*>(out_sel + (size_t)t * TOPK) = e;
        e.x = (float)selE[4]; e.y = (float)selE[5];
        e.z = (float)selE[6]; e.w = (float)selE[7];
        *reinterpret_cast<float4*>(out_sel + (size_t)t * TOPK + 4) = e;
#pragma unroll
        for (int kk = 0; kk < TOPK; kk++)
          atomicAdd(&out_counts[selE[kk]], 1.0f);
      }
    }
    __syncthreads();
  }
}

extern "C" void kernel_launch(void* const* d_in, const int* in_sizes, int n_in,
                              void* d_out, int out_size, void* d_ws, size_t ws_size,
                              hipStream_t stream) {
  const float* x = (const float*)d_in[0];
  const float* w = (const float*)d_in[1];
  const float* bias = (const float*)d_in[2];
  float* out = (float*)d_out;
  float* out_scores = out;
  float* out_sel = out + T_TOK * TOPK;
  float* out_counts = out + 2 * T_TOK * TOPK;

  char* ws = (char*)d_ws;
  float* scores = (float*)ws;                                   // 16 MiB
  _Float16* wh = (_Float16*)(ws + (size_t)16 * 1024 * 1024);    // 1 MiB
  _Float16* wlo = (_Float16*)(ws + (size_t)17 * 1024 * 1024);   // 1 MiB
  int* wl_count = (int*)(ws + (size_t)18 * 1024 * 1024);
  int* wlist = wl_count + 16;
  double* scG = (double*)(ws + (size_t)19 * 1024 * 1024);       // <= 12.6 MiB

  prep<<<2048, 256, 0, stream>>>(w, wh, wlo, out_counts, wl_count);
  gate_gemm_mfma<<<512, 256, 0, stream>>>(x, wh, wlo, scores);
  router_serial<<<T_TOK / 64, 64, 0, stream>>>(scores, bias, out_scores,
                                               out_sel, out_counts, wl_count,
                                               wlist);
  fixup_logits<<<2048, 256, 0, stream>>>(x, w, wl_count, wlist, scG);
  fixup_select<<<2048, 256, 0, stream>>>(scG, x, w, bias, out_scores, out_sel,
                                         out_counts, wl_count, wlist);
}

// Round 17
// 131.721 us; speedup vs baseline: 28.1315x; 1.2089x over previous
//
#include <hip/hip_runtime.h>
#include <math.h>
#include <stdint.h>

#define T_TOK 16384
#define DDIM 2048
#define NEXP 256
#define TOPK 8
#define NLIM 4
#define CAPN 6144

constexpr float EPSC = 5e-6f;         // certified score-space error bound
constexpr float SCL = 1.f / 4096.f;   // undo x*16, w*256 scaling

typedef _Float16 half4v __attribute__((ext_vector_type(4)));
typedef _Float16 half8v __attribute__((ext_vector_type(8)));
typedef float f32x4 __attribute__((ext_vector_type(4)));

__device__ __forceinline__ void gload16(const _Float16* g, _Float16* l) {
  __builtin_amdgcn_global_load_lds(
      (const __attribute__((address_space(1))) void*)g,
      (__attribute__((address_space(3))) void*)(uint32_t)(size_t)l, 16, 0, 0);
}

// --- K0: convert w to fp16 hi/lo in TILE-PERMUTED (pre-swizzled) layout ----
// whS[p*262144 + t*8192 + h] = split(w[(p*128 + (h>>6)) , t*64 + ((h&63)^(((h>>6)&7)<<3))])
__global__ __launch_bounds__(256) void prep(
    const float* __restrict__ w, _Float16* __restrict__ whS,
    _Float16* __restrict__ wloS, float* __restrict__ counts,
    int* __restrict__ wl_count) {
  int gid = blockIdx.x * 256 + threadIdx.x;   // 524288 threads
  int p = gid >> 18;
  int rem = gid & 262143;
  int t = rem >> 13;
  int h = rem & 8191;
  int row = h >> 6;
  int kl = (h & 63) ^ ((row & 7) << 3);
  float W = w[(size_t)(p * 128 + row) * DDIM + t * 64 + kl] * 256.f;
  _Float16 hh = (_Float16)W;
  whS[gid] = hh;
  wloS[gid] = (_Float16)(W - (float)hh);
  if (blockIdx.x == 0) {
    counts[threadIdx.x] = 0.f;
    if (threadIdx.x == 0) *wl_count = 0;
  }
}

// --- K1: MFMA gate GEMM: A reg-staged, B direct global_load_lds (swizzled) -
constexpr int BM = 64, BN = 128, BK = 64, NT = DDIM / BK;  // NT=32
__global__ __launch_bounds__(256) void gate_gemm_mfma(
    const float* __restrict__ x, const _Float16* __restrict__ whS,
    const _Float16* __restrict__ wloS, float* __restrict__ scores) {
  __shared__ _Float16 Ah[64][72], Al[64][72];   // 18432 B
  __shared__ _Float16 BhL[8192], BlL[8192];     // 32768 B (linear, swizzled)
  const int tid = threadIdx.x;
  const int bid = blockIdx.x;
  const int swz = (bid & 7) * 64 + (bid >> 3);  // bijective XCD swizzle
  const int mb = swz >> 1, nb = swz & 1;
  const int row0 = mb * BM, col0 = nb * BN;
  const int wave = tid >> 6, lane = tid & 63;
  const int m0 = (wave >> 1) * 32, n0 = (wave & 1) * 64;

  f32x4 acc[2][4];
#pragma unroll
  for (int i = 0; i < 2; i++)
#pragma unroll
    for (int j = 0; j < 4; j++) acc[i][j] = (f32x4){0.f, 0.f, 0.f, 0.f};

  float4 ar[4];

  auto LOADA = [&](int t) {
    const int k0 = t * BK;
#pragma unroll
    for (int i = 0; i < 4; i++) {
      int f = i * 256 + tid;
      int r = f >> 4, c4 = (f & 15) << 2;
      ar[i] = *reinterpret_cast<const float4*>(
          x + (size_t)(row0 + r) * DDIM + k0 + c4);
    }
  };
  auto WRITEA = [&]() {
#pragma unroll
    for (int i = 0; i < 4; i++) {
      int f = i * 256 + tid;
      int r = f >> 4, c4 = (f & 15) << 2;
      float4 v = ar[i];
      float X0 = v.x * 16.f, X1 = v.y * 16.f, X2 = v.z * 16.f, X3 = v.w * 16.f;
      _Float16 h0 = (_Float16)X0, h1 = (_Float16)X1;
      _Float16 h2 = (_Float16)X2, h3 = (_Float16)X3;
      half4v hv = {h0, h1, h2, h3};
      half4v lv = {(_Float16)(X0 - (float)h0), (_Float16)(X1 - (float)h1),
                   (_Float16)(X2 - (float)h2), (_Float16)(X3 - (float)h3)};
      *reinterpret_cast<half4v*>(&Ah[r][c4]) = hv;
      *reinterpret_cast<half4v*>(&Al[r][c4]) = lv;
    }
  };
  auto GLOADB = [&](int t) {
    const size_t base = (size_t)nb * 262144 + (size_t)t * 8192 +
                        (size_t)(wave * 4) * 512 + (size_t)lane * 8;
    const _Float16* sh = whS + base;
    const _Float16* sl = wloS + base;
#pragma unroll
    for (int i = 0; i < 4; i++) {
      gload16(sh + i * 512, &BhL[(wave * 4 + i) * 512]);
      gload16(sl + i * 512, &BlL[(wave * 4 + i) * 512]);
    }
  };

  LOADA(0);
  for (int t = 0; t < NT; t++) {
    GLOADB(t);        // direct-to-LDS, drained by the barrier below
    WRITEA();         // waits only on A loads (older than the gloads)
    __syncthreads();
    if (t + 1 < NT) LOADA(t + 1);  // next A tile in flight under compute
#pragma unroll
    for (int ks = 0; ks < 2; ks++) {
      const int koff = ks * 32 + (lane >> 4) * 8;     // halves (A)
      const int kb = ks * 64 + ((lane >> 4) * 16);    // bytes (B natural)
      half8v ah[2], al[2], bh[4], bl[4];
#pragma unroll
      for (int mf = 0; mf < 2; mf++) {
        int r = m0 + mf * 16 + (lane & 15);
        ah[mf] = *reinterpret_cast<half8v*>(&Ah[r][koff]);
        al[mf] = *reinterpret_cast<half8v*>(&Al[r][koff]);
      }
#pragma unroll
      for (int nf = 0; nf < 4; nf++) {
        int c = n0 + nf * 16 + (lane & 15);
        int ab = (c << 7) + (kb ^ ((c & 7) << 4));   // swizzled byte offset
        bh[nf] = *reinterpret_cast<half8v*>((char*)BhL + ab);
        bl[nf] = *reinterpret_cast<half8v*>((char*)BlL + ab);
      }
#pragma unroll
      for (int mf = 0; mf < 2; mf++)
#pragma unroll
        for (int nf = 0; nf < 4; nf++) {
          acc[mf][nf] = __builtin_amdgcn_mfma_f32_16x16x32_f16(
              ah[mf], bh[nf], acc[mf][nf], 0, 0, 0);
          acc[mf][nf] = __builtin_amdgcn_mfma_f32_16x16x32_f16(
              ah[mf], bl[nf], acc[mf][nf], 0, 0, 0);
          acc[mf][nf] = __builtin_amdgcn_mfma_f32_16x16x32_f16(
              al[mf], bh[nf], acc[mf][nf], 0, 0, 0);
        }
    }
    __syncthreads();
  }
  // epilogue: sigmoid, plain stores
#pragma unroll
  for (int mf = 0; mf < 2; mf++)
#pragma unroll
    for (int nf = 0; nf < 4; nf++)
#pragma unroll
      for (int r = 0; r < 4; r++) {
        int row = row0 + m0 + mf * 16 + (lane >> 4) * 4 + r;
        int col = col0 + n0 + nf * 16 + (lane & 15);
        float sv = 1.f / (1.f + expf(-acc[mf][nf][r] * SCL));
        scores[(size_t)row * NEXP + col] = sv;
      }
}

// -------- K2: serial-lane router: one lane per token, u64-key top-9 --------
__global__ __launch_bounds__(64) void router_serial(
    const float* __restrict__ scores, const float* __restrict__ bias,
    float* __restrict__ out_scores, float* __restrict__ out_sel,
    float* __restrict__ out_counts, int* __restrict__ wl_count,
    int* __restrict__ wlist) {
  __shared__ float S[64][257];
  __shared__ float BS[256];
  __shared__ int hist[256];
  const int lane = threadIdx.x;
  const int t0 = blockIdx.x * 64;

#pragma unroll
  for (int i = 0; i < 4; i++) {
    hist[i * 64 + lane] = 0;
    BS[i * 64 + lane] = bias[i * 64 + lane];
  }
  float4 bv = *reinterpret_cast<const float4*>(bias + lane * 4);
  for (int r = 0; r < 64; r++) {
    float4 v = *reinterpret_cast<const float4*>(
        scores + (size_t)(t0 + r) * NEXP + lane * 4);
    S[r][lane * 4 + 0] = v.x + bv.x;
    S[r][lane * 4 + 1] = v.y + bv.y;
    S[r][lane * 4 + 2] = v.z + bv.z;
    S[r][lane * 4 + 3] = v.w + bv.w;
  }
  __syncthreads();

  const float* Srow = S[lane];
  const int t = t0 + lane;

  float gsArr[8];
#pragma unroll
  for (int g = 0; g < 8; g++) {
    float m1 = -INFINITY, m2 = -INFINITY;
#pragma unroll 4
    for (int k = 0; k < 32; k++) {
      float c = Srow[g * 32 + k];
      float mx = fmaxf(m1, c);
      m2 = fmaxf(m2, fminf(m1, c));
      m1 = mx;
    }
    gsArr[g] = m1 + m2;
  }

  int kgpack = 0;
  float v4 = 0.f, v5 = 0.f;
#pragma unroll
  for (int g = 7; g >= 0; g--) {
    int rk = 0;
#pragma unroll
    for (int h = 0; h < 8; h++)
      rk += (gsArr[h] > gsArr[g]) || (gsArr[h] == gsArr[g] && h < g);
    if (rk < NLIM) kgpack = (kgpack << 4) | g;
    if (rk == 3) v4 = gsArr[g];
    if (rk == 4) v5 = gsArr[g];
  }
  bool flag = (v4 - v5) < 8.f * EPSC;

  unsigned long long L[9];
#pragma unroll
  for (int i = 0; i < 9; i++) L[i] = 0ULL;
#pragma unroll
  for (int gi = 0; gi < 4; gi++) {
    const int cb = ((kgpack >> (gi * 4)) & 15) * 32;
#pragma unroll 2
    for (int k = 0; k < 32; k++) {
      float c = Srow[cb + k];
      unsigned int bits = __float_as_uint(c + 1.0f);
      unsigned long long key =
          ((unsigned long long)bits << 8) | (unsigned)(255 - (cb + k));
#pragma unroll
      for (int sl = 0; sl < 9; sl++) {
        bool gt = key > L[sl];
        unsigned long long nl = gt ? key : L[sl];
        key = gt ? L[sl] : key;
        L[sl] = nl;
      }
    }
  }

  int selE[9];
  float cval[9];
#pragma unroll
  for (int i = 0; i < 9; i++) {
    selE[i] = 255 - (int)(L[i] & 0xFFULL);
    cval[i] = __uint_as_float((unsigned)(L[i] >> 8)) - 1.0f;
  }
#pragma unroll
  for (int i = 0; i < 8; i++)
    flag = flag || ((cval[i] - cval[i + 1]) < 2.f * EPSC);

  if (!flag) {
    float s[8];
    float denom = 1e-20f;
#pragma unroll
    for (int i = 0; i < 8; i++) {
      s[i] = Srow[selE[i]] - BS[selE[i]];
      denom += s[i];
    }
    float scale = 2.5f / denom;
    float4 o0 = {s[0] * scale, s[1] * scale, s[2] * scale, s[3] * scale};
    float4 o1 = {s[4] * scale, s[5] * scale, s[6] * scale, s[7] * scale};
    *reinterpret_cast<float4*>(out_scores + (size_t)t * TOPK) = o0;
    *reinterpret_cast<float4*>(out_scores + (size_t)t * TOPK + 4) = o1;
    float4 e0 = {(float)selE[0], (float)selE[1], (float)selE[2], (float)selE[3]};
    float4 e1 = {(float)selE[4], (float)selE[5], (float)selE[6], (float)selE[7]};
    *reinterpret_cast<float4*>(out_sel + (size_t)t * TOPK) = e0;
    *reinterpret_cast<float4*>(out_sel + (size_t)t * TOPK + 4) = e1;
#pragma unroll
    for (int i = 0; i < 8; i++) atomicAdd(&hist[selE[i]], 1);
  } else {
    int i = atomicAdd(wl_count, 1);
    wlist[i] = t;
  }
  __syncthreads();
#pragma unroll
  for (int i = 0; i < 4; i++) {
    int h = hist[i * 64 + lane];
    if (h) atomicAdd(&out_counts[i * 64 + lane], (float)h);
  }
}

// ---- K3a: f64 logits for flagged tokens; block = (token-quad, 16 experts) -
__global__ __launch_bounds__(256) void fixup_logits(
    const float* __restrict__ x, const float* __restrict__ w,
    const int* __restrict__ wl_count, const int* __restrict__ wlist,
    double* __restrict__ scG) {
  __shared__ float xs[4][DDIM];
  __shared__ int toks[4];
  const int n = min(*wl_count, CAPN);
  const int nq = (n + 3) >> 2;
  const int nwork = nq * 16;
  const int tid = threadIdx.x;
  const int wv = tid >> 6, lane = tid & 63;

  for (int wk = blockIdx.x; wk < nwork; wk += gridDim.x) {
    const int q = wk >> 4, ec = wk & 15;
    __syncthreads();
    if (tid < 4) {
      int idx = q * 4 + tid;
      toks[tid] = wlist[idx < n ? idx : (n - 1)];
    }
    __syncthreads();
    for (int i = tid; i < 4 * 512; i += 256) {
      int tk = i >> 9, off = i & 511;
      reinterpret_cast<float4*>(xs[tk])[off] =
          reinterpret_cast<const float4*>(x + (size_t)toks[tk] * DDIM)[off];
    }
    __syncthreads();

#pragma unroll 1
    for (int ei = 0; ei < 4; ei++) {
      const int e = ec * 16 + wv * 4 + ei;
      const float* wr = w + (size_t)e * DDIM + lane * 4;
      float4 wreg[8];
#pragma unroll
      for (int j = 0; j < 8; j++)
        wreg[j] = *reinterpret_cast<const float4*>(wr + j * 256);
      double p0 = 0, p1 = 0, p2 = 0, p3 = 0;
#pragma unroll
      for (int j = 0; j < 8; j++) {
        const int k = j * 256 + lane * 4;
        float4 wv4 = wreg[j];
        float4 x0 = *reinterpret_cast<const float4*>(&xs[0][k]);
        float4 x1 = *reinterpret_cast<const float4*>(&xs[1][k]);
        float4 x2 = *reinterpret_cast<const float4*>(&xs[2][k]);
        float4 x3 = *reinterpret_cast<const float4*>(&xs[3][k]);
        p0 = fma((double)x0.x, (double)wv4.x, p0);
        p0 = fma((double)x0.y, (double)wv4.y, p0);
        p0 = fma((double)x0.z, (double)wv4.z, p0);
        p0 = fma((double)x0.w, (double)wv4.w, p0);
        p1 = fma((double)x1.x, (double)wv4.x, p1);
        p1 = fma((double)x1.y, (double)wv4.y, p1);
        p1 = fma((double)x1.z, (double)wv4.z, p1);
        p1 = fma((double)x1.w, (double)wv4.w, p1);
        p2 = fma((double)x2.x, (double)wv4.x, p2);
        p2 = fma((double)x2.y, (double)wv4.y, p2);
        p2 = fma((double)x2.z, (double)wv4.z, p2);
        p2 = fma((double)x2.w, (double)wv4.w, p2);
        p3 = fma((double)x3.x, (double)wv4.x, p3);
        p3 = fma((double)x3.y, (double)wv4.y, p3);
        p3 = fma((double)x3.z, (double)wv4.z, p3);
        p3 = fma((double)x3.w, (double)wv4.w, p3);
      }
#pragma unroll
      for (int d = 1; d <= 32; d <<= 1) {
        p0 += __shfl_xor(p0, d);
        p1 += __shfl_xor(p1, d);
        p2 += __shfl_xor(p2, d);
        p3 += __shfl_xor(p3, d);
      }
      if (lane == 0) {
        const int it0 = q * 4;
        if (it0 + 0 < n) scG[(size_t)(it0 + 0) * NEXP + e] = 1.0 / (1.0 + exp(-p0));
        if (it0 + 1 < n) scG[(size_t)(it0 + 1) * NEXP + e] = 1.0 / (1.0 + exp(-p1));
        if (it0 + 2 < n) scG[(size_t)(it0 + 2) * NEXP + e] = 1.0 / (1.0 + exp(-p2));
        if (it0 + 3 < n) scG[(size_t)(it0 + 3) * NEXP + e] = 1.0 / (1.0 + exp(-p3));
      }
    }
  }
}

// ---- K3b: exact f64 selection per flagged token (reads scG) ---------------
__global__ __launch_bounds__(256) void fixup_select(
    const double* __restrict__ scG, const float* __restrict__ x,
    const float* __restrict__ w, const float* __restrict__ bias,
    float* __restrict__ out_scores, float* __restrict__ out_sel,
    float* __restrict__ out_counts, const int* __restrict__ wl_count,
    const int* __restrict__ wlist) {
  __shared__ double sc[NEXP];
  const int n = *wl_count;
  const int tid = threadIdx.x;
  const int wv = tid >> 6, lane = tid & 63;

  for (int it = blockIdx.x; it < n; it += gridDim.x) {
    const int t = wlist[it];
    __syncthreads();
    if (it < CAPN) {
      sc[tid] = scG[(size_t)it * NEXP + tid];
    } else {
      const float* xrow = x + (size_t)t * DDIM + lane * 8;
      float4 xr[4][2];
#pragma unroll
      for (int p = 0; p < 4; p++) {
        xr[p][0] = *reinterpret_cast<const float4*>(xrow + p * 512);
        xr[p][1] = *reinterpret_cast<const float4*>(xrow + p * 512 + 4);
      }
      double myLogit = 0.0;
      for (int e = 0; e < 64; e++) {
        const float* wr = w + (size_t)(wv * 64 + e) * DDIM + lane * 8;
        double a0 = 0, a1 = 0;
#pragma unroll
        for (int p = 0; p < 4; p++) {
          float4 w0 = *reinterpret_cast<const float4*>(wr + p * 512);
          float4 w1 = *reinterpret_cast<const float4*>(wr + p * 512 + 4);
          a0 = fma((double)xr[p][0].x, (double)w0.x, a0);
          a1 = fma((double)xr[p][0].y, (double)w0.y, a1);
          a0 = fma((double)xr[p][0].z, (double)w0.z, a0);
          a1 = fma((double)xr[p][0].w, (double)w0.w, a1);
          a0 = fma((double)xr[p][1].x, (double)w1.x, a0);
          a1 = fma((double)xr[p][1].y, (double)w1.y, a1);
          a0 = fma((double)xr[p][1].z, (double)w1.z, a0);
          a1 = fma((double)xr[p][1].w, (double)w1.w, a1);
        }
        double tot = a0 + a1;
#pragma unroll
        for (int d = 1; d <= 32; d <<= 1) tot += __shfl_xor(tot, d);
        if (lane == e) myLogit = tot;
      }
      sc[wv * 64 + lane] = 1.0 / (1.0 + exp(-myLogit));
    }
    __syncthreads();

    if (tid < 64) {
      double s[4], c[4];
      s[0] = sc[lane * 4 + 0]; s[1] = sc[lane * 4 + 1];
      s[2] = sc[lane * 4 + 2]; s[3] = sc[lane * 4 + 3];
      float4 bvv = *reinterpret_cast<const float4*>(bias + lane * 4);
      c[0] = s[0] + (double)bvv.x; c[1] = s[1] + (double)bvv.y;
      c[2] = s[2] + (double)bvv.z; c[3] = s[3] + (double)bvv.w;

      double h1 = fmax(c[0], c[1]), l1 = fmin(c[0], c[1]);
      double h2 = fmax(c[2], c[3]), l2 = fmin(c[2], c[3]);
      double m1 = fmax(h1, h2);
      double m2 = fmax(fmin(h1, h2), fmax(l1, l2));
#pragma unroll
      for (int d = 1; d <= 4; d <<= 1) {
        double om1 = __shfl_xor(m1, d);
        double om2 = __shfl_xor(m2, d);
        double n1 = fmax(m1, om1);
        double n2 = fmax(fmin(m1, om1), fmax(m2, om2));
        m1 = n1; m2 = n2;
      }
      double gscore = m1 + m2;
      double gsv[8];
#pragma unroll
      for (int g = 0; g < 8; g++) gsv[g] = __shfl(gscore, g * 8);
      const int gme = lane >> 3;
      int rank = 0;
#pragma unroll
      for (int h = 0; h < 8; h++)
        rank += (gsv[h] > gsv[gme]) || (gsv[h] == gsv[gme] && h < gme);
      const bool keep = rank < NLIM;

      const double NEG = -HUGE_VAL;
      double v[4];
#pragma unroll
      for (int j = 0; j < 4; j++) v[j] = keep ? c[j] : NEG;

      double selS[TOPK];
      int selE[TOPK];
#pragma unroll
      for (int kk = 0; kk < TOPK; kk++) {
        double bvv2 = v[0];
        int bi = lane * 4;
#pragma unroll
        for (int j = 1; j < 4; j++)
          if (v[j] > bvv2) { bvv2 = v[j]; bi = lane * 4 + j; }
#pragma unroll
        for (int d = 1; d <= 32; d <<= 1) {
          double ov = __shfl_xor(bvv2, d);
          int oi = __shfl_xor(bi, d);
          if (ov > bvv2 || (ov == bvv2 && oi < bi)) { bvv2 = ov; bi = oi; }
        }
        selE[kk] = bi;
        int ol = bi >> 2, oj = bi & 3;
        double cand = (oj == 0) ? s[0] : (oj == 1) ? s[1] : (oj == 2) ? s[2] : s[3];
        selS[kk] = __shfl(cand, ol);
#pragma unroll
        for (int j = 0; j < 4; j++)
          if (lane == ol && j == oj) v[j] = NEG;
      }

      double denom = 1e-20;
#pragma unroll
      for (int kk = 0; kk < TOPK; kk++) denom += selS[kk];
      double scale = 2.5 / denom;

      if (lane == 0) {
        float4 o;
        o.x = (float)(selS[0] * scale); o.y = (float)(selS[1] * scale);
        o.z = (float)(selS[2] * scale); o.w = (float)(selS[3] * scale);
        *reinterpret_cast<float4*>(out_scores + (size_t)t * TOPK) = o;
        o.x = (float)(selS[4] * scale); o.y = (float)(selS[5] * scale);
        o.z = (float)(selS[6] * scale); o.w = (float)(selS[7] * scale);
        *reinterpret_cast<float4*>(out_scores + (size_t)t * TOPK + 4) = o;
        float4 e;
        e.x = (float)selE[0]; e.y = (float)selE[1];
        e.z = (float)selE[2]; e.w = (float)selE[3];
        *reinterpret_cast<float4*>(out_sel + (size_t)t * TOPK) = e;
        e.x = (float)selE[4]; e.y = (float)selE[5];
        e.z = (float)selE[6]; e.w = (float)selE[7];
        *reinterpret_cast<float4*>(out_sel + (size_t)t * TOPK + 4) = e;
#pragma unroll
        for (int kk = 0; kk < TOPK; kk++)
          atomicAdd(&out_counts[selE[kk]], 1.0f);
      }
    }
    __syncthreads();
  }
}

extern "C" void kernel_launch(void* const* d_in, const int* in_sizes, int n_in,
                              void* d_out, int out_size, void* d_ws, size_t ws_size,
                              hipStream_t stream) {
  const float* x = (const float*)d_in[0];
  const float* w = (const float*)d_in[1];
  const float* bias = (const float*)d_in[2];
  float* out = (float*)d_out;
  float* out_scores = out;
  float* out_sel = out + T_TOK * TOPK;
  float* out_counts = out + 2 * T_TOK * TOPK;

  char* ws = (char*)d_ws;
  float* scores = (float*)ws;                                   // 16 MiB
  _Float16* whS = (_Float16*)(ws + (size_t)16 * 1024 * 1024);   // 1 MiB
  _Float16* wloS = (_Float16*)(ws + (size_t)17 * 1024 * 1024);  // 1 MiB
  int* wl_count = (int*)(ws + (size_t)18 * 1024 * 1024);
  int* wlist = wl_count + 16;
  double* scG = (double*)(ws + (size_t)19 * 1024 * 1024);       // <= 12.6 MiB

  prep<<<2048, 256, 0, stream>>>(w, whS, wloS, out_counts, wl_count);
  gate_gemm_mfma<<<512, 256, 0, stream>>>(x, whS, wloS, scores);
  router_serial<<<T_TOK / 64, 64, 0, stream>>>(scores, bias, out_scores,
                                               out_sel, out_counts, wl_count,
                                               wlist);
  fixup_logits<<<2048, 256, 0, stream>>>(x, w, wl_count, wlist, scG);
  fixup_select<<<2048, 256, 0, stream>>>(scG, x, w, bias, out_scores, out_sel,
                                         out_counts, wl_count, wlist);
}